// Round 1
// baseline (354.703 us; speedup 1.0000x reference)
//
#include <hip/hip_runtime.h>
#include <hip/hip_bf16.h>
#include <cmath>

// Problem constants
#define BATCH   4096
#define NUNITS  1024
#define INSIZE  512
#define SIGSZ   6
#define KSIG    (NUNITS * SIGSZ)          // 6144
#define SAVED   (KSIG + NUNITS)           // 7168
#define KTOT    (INSIZE + KSIG + NUNITS)  // 7680
#define OUTW    (NUNITS * (SIGSZ + 1))    // 7168

// Tile config
#define BM 128
#define BN 128
#define BK 64
#define LDK 72          // padded LDS row (bf16 elems): 144B row stride -> conflict-free-ish
#define NKT (KTOT / BK) // 120

typedef __attribute__((ext_vector_type(8))) short bf16x8;
typedef __attribute__((ext_vector_type(4))) float f32x4;

__device__ __forceinline__ unsigned short f2bf(float f) {
    union { float f; unsigned int u; } c; c.f = f;
    unsigned int u = c.u;
    return (unsigned short)((u + 0x7FFFu + ((u >> 16) & 1u)) >> 16);  // RNE
}

__global__ __launch_bounds__(256)
void rsig_fused(const float* __restrict__ x,
                const float* __restrict__ sigs,
                const float* __restrict__ states,
                const float* __restrict__ Ww,
                const float* __restrict__ Wb,
                const float* __restrict__ Uw,
                const float* __restrict__ Ub,
                const float* __restrict__ lt,
                float* __restrict__ out)
{
    __shared__ unsigned short lA[BM][LDK];
    __shared__ unsigned short lB[BN][LDK];

    const int t   = threadIdx.x;
    const int bid = blockIdx.x;
    const int bn  = bid & 7;    // N / BN = 8 column tiles
    const int bm  = bid >> 3;   // 32 row tiles

    const int lane = t & 63;
    const int w    = t >> 6;    // wave 0..3
    const int wm   = w >> 1;    // 2x2 wave grid, each wave does 64x64
    const int wn   = w & 1;

    const int srow = t >> 4;    // staging: 16 rows per pass
    const int sc4  = t & 15;    // 16 float4 columns cover BK=64

    f32x4 acc[4][4];
#pragma unroll
    for (int m = 0; m < 4; ++m)
#pragma unroll
        for (int n = 0; n < 4; ++n)
            acc[m][n] = (f32x4)0.f;

    for (int kt = 0; kt < NKT; ++kt) {
        // A source: virtual K = [x (512) | prev_sigs (6144) | prev_states (1024)]
        const float* abase; int astr, koff;
        if (kt < 8)        { abase = x;      astr = INSIZE; koff = kt * BK; }
        else if (kt < 104) { abase = sigs;   astr = KSIG;   koff = kt * BK - 512; }
        else               { abase = states; astr = NUNITS; koff = kt * BK - 6656; }
        // B source: [W_w (512) | U_w (7168)]
        const float* bbase; int bstr, koffb;
        if (kt < 8)        { bbase = Ww; bstr = INSIZE; koffb = kt * BK; }
        else               { bbase = Uw; bstr = SAVED;  koffb = kt * BK - 512; }

#pragma unroll
        for (int i = 0; i < 8; ++i) {
            const int rr = srow + i * 16;
            const float4 va = *(const float4*)(abase + (size_t)(bm * BM + rr) * astr + koff  + sc4 * 4);
            const float4 vb = *(const float4*)(bbase + (size_t)(bn * BN + rr) * bstr + koffb + sc4 * 4);
            ushort4 ha, hb;
            ha.x = f2bf(va.x); ha.y = f2bf(va.y); ha.z = f2bf(va.z); ha.w = f2bf(va.w);
            hb.x = f2bf(vb.x); hb.y = f2bf(vb.y); hb.z = f2bf(vb.z); hb.w = f2bf(vb.w);
            *(ushort4*)&lA[rr][sc4 * 4] = ha;
            *(ushort4*)&lB[rr][sc4 * 4] = hb;
        }
        __syncthreads();

#pragma unroll
        for (int ks = 0; ks < 2; ++ks) {
            bf16x8 af[4], bfr[4];
#pragma unroll
            for (int m = 0; m < 4; ++m)
                af[m] = *(const bf16x8*)&lA[wm * 64 + m * 16 + (lane & 15)][ks * 32 + (lane >> 4) * 8];
#pragma unroll
            for (int n = 0; n < 4; ++n)
                bfr[n] = *(const bf16x8*)&lB[wn * 64 + n * 16 + (lane & 15)][ks * 32 + (lane >> 4) * 8];
#pragma unroll
            for (int m = 0; m < 4; ++m)
#pragma unroll
                for (int n = 0; n < 4; ++n)
                    acc[m][n] = __builtin_amdgcn_mfma_f32_16x16x32_bf16(af[m], bfr[n], acc[m][n], 0, 0, 0);
        }
        __syncthreads();
    }

    // Epilogue: raw = acc + biases; fused sigjoin (level 2) + outputs
    const float tl = expf(lt[0]);
#pragma unroll
    for (int n = 0; n < 4; ++n) {
        const int u = bn * BN + wn * 64 + n * 16 + (lane & 15);
        const float bias = Wb[u] + Ub[u];
#pragma unroll
        for (int m = 0; m < 4; ++m) {
            const int rb = bm * BM + wm * 64 + m * 16 + ((lane >> 4) << 2);
#pragma unroll
            for (int i = 0; i < 4; ++i) {
                const int b = rb + i;
                const float raw = acc[m][n][i] + bias;
                const float ps  = states[(size_t)b * NUNITS + u];
                const float d   = raw - ps;
                const float* s  = sigs + (size_t)b * KSIG + u * 6;
                const float s0 = s[0], s1 = s[1], s2 = s[2], s3 = s[3], s4 = s[4], s5 = s[5];
                float* o = out + (size_t)b * OUTW + u * 6;
                o[0] = s0 + d;
                o[1] = s1 + tl;
                o[2] = s2 + 0.5f * d * d   + s0 * d;
                o[3] = s3 + 0.5f * d * tl  + s0 * tl;
                o[4] = s4 + 0.5f * tl * d  + s1 * d;
                o[5] = s5 + 0.5f * tl * tl + s1 * tl;
                out[(size_t)b * OUTW + KSIG + u] = raw;
            }
        }
    }
}

extern "C" void kernel_launch(void* const* d_in, const int* in_sizes, int n_in,
                              void* d_out, int out_size, void* d_ws, size_t ws_size,
                              hipStream_t stream) {
    const float* x      = (const float*)d_in[0];
    const float* sigs   = (const float*)d_in[1];
    const float* states = (const float*)d_in[2];
    const float* Ww     = (const float*)d_in[3];
    const float* Wb     = (const float*)d_in[4];
    const float* Uw     = (const float*)d_in[5];
    const float* Ub     = (const float*)d_in[6];
    const float* lt     = (const float*)d_in[7];
    float* out = (float*)d_out;

    dim3 grid((BATCH / BM) * (NUNITS / BN));  // 32 * 8 = 256 blocks
    dim3 block(256);
    hipLaunchKernelGGL(rsig_fused, grid, block, 0, stream,
                       x, sigs, states, Ww, Wb, Uw, Ub, lt, out);
}